// Round 1
// baseline (821.708 us; speedup 1.0000x reference)
//
#include <hip/hip_runtime.h>
#include <hip/hip_bf16.h>

#define DM   768
#define NH   12
#define HD   64
#define NTOK 1024
#define FFD  3072
#define WIN  125

typedef __bf16 bf16x8 __attribute__((ext_vector_type(8)));
typedef __attribute__((ext_vector_type(4))) float f32x4;

__device__ inline ushort f2bf(float f) {
  union { float f; uint u; } v; v.f = f;
  uint u = v.u;
  uint r = (u + 0x7FFFu + ((u >> 16) & 1u)) >> 16;
  return (ushort)r;
}
__device__ inline float bf2f(ushort h) {
  union { uint u; float f; } v; v.u = ((uint)h) << 16;
  return v.f;
}

// ---------------- fp32 -> bf16 weight conversion ----------------
__global__ void cvt_kernel(const float* __restrict__ in, ushort* __restrict__ out, int n4) {
  int i = blockIdx.x * blockDim.x + threadIdx.x;
  int stride = gridDim.x * blockDim.x;
  for (; i < n4; i += stride) {
    float4 v = ((const float4*)in)[i];
    ushort4 o;
    o.x = f2bf(v.x); o.y = f2bf(v.y); o.z = f2bf(v.z); o.w = f2bf(v.w);
    ((ushort4*)out)[i] = o;
  }
}

// ---------------- RMSNorm (one block per row) ----------------
__global__ __launch_bounds__(256) void rmsnorm_kernel(
    const float* __restrict__ x, const float* __restrict__ w,
    ushort* __restrict__ outB, float* __restrict__ outF) {
  int row = blockIdx.x;
  const float* xr = x + row * DM;
  int tid = threadIdx.x;
  float v0 = xr[tid], v1 = xr[tid + 256], v2 = xr[tid + 512];
  float ss = v0 * v0 + v1 * v1 + v2 * v2;
  for (int off = 32; off; off >>= 1) ss += __shfl_xor(ss, off, 64);
  __shared__ float red[4];
  int wid = tid >> 6;
  if ((tid & 63) == 0) red[wid] = ss;
  __syncthreads();
  float tot = red[0] + red[1] + red[2] + red[3];
  float scale = rsqrtf(tot * (1.0f / DM) + 1e-6f);
  float o0 = v0 * scale * w[tid];
  float o1 = v1 * scale * w[tid + 256];
  float o2 = v2 * scale * w[tid + 512];
  if (outB) {
    outB[row * DM + tid]       = f2bf(o0);
    outB[row * DM + tid + 256] = f2bf(o1);
    outB[row * DM + tid + 512] = f2bf(o2);
  } else {
    outF[row * DM + tid]       = o0;
    outF[row * DM + tid + 256] = o1;
    outF[row * DM + tid + 512] = o2;
  }
}

// ---------------- bf16 MFMA GEMM: C[M,N] = A[M,K] @ B[N,K]^T (+bias)(+resid) ----------------
// one wave per 64x64 tile; fragments loaded directly from global (L2/L3-resident problem)
__global__ __launch_bounds__(64) void gemm64(
    const ushort* __restrict__ A, const ushort* __restrict__ B,
    const float* __restrict__ bias, const float* __restrict__ resid,
    float* __restrict__ outF, ushort* __restrict__ outB,
    int M, int N, int K) {
  int n0 = blockIdx.x * 64;
  int m0 = blockIdx.y * 64;
  int lane = threadIdx.x;
  int r  = lane & 15;
  int kg = lane >> 4;

  f32x4 acc[4][4] = {};
  const ushort* Ab = A + (m0 + r) * K + kg * 8;
  const ushort* Bb = B + (n0 + r) * K + kg * 8;

  for (int k = 0; k < K; k += 32) {
    bf16x8 a[4], b[4];
#pragma unroll
    for (int i = 0; i < 4; ++i) {
      a[i] = *(const bf16x8*)(Ab + i * 16 * K + k);
      b[i] = *(const bf16x8*)(Bb + i * 16 * K + k);
    }
#pragma unroll
    for (int mi = 0; mi < 4; ++mi)
#pragma unroll
      for (int ni = 0; ni < 4; ++ni)
        acc[mi][ni] = __builtin_amdgcn_mfma_f32_16x16x32_bf16(a[mi], b[ni], acc[mi][ni], 0, 0, 0);
  }

  int crow = m0 + (lane >> 4) * 4;
  int ccol = n0 + (lane & 15);
#pragma unroll
  for (int mi = 0; mi < 4; ++mi)
#pragma unroll
    for (int ni = 0; ni < 4; ++ni) {
      int col = ccol + ni * 16;
      float bv = bias ? bias[col] : 0.0f;
#pragma unroll
      for (int q = 0; q < 4; ++q) {
        int row = crow + mi * 16 + q;
        int idx = row * N + col;
        float val = acc[mi][ni][q] + bv;
        if (resid) val += resid[idx];
        if (outF) outF[idx] = val;
        else      outB[idx] = f2bf(val);
      }
    }
}

// ---------------- 3D neighborhood attention: one block per (token, head) ----------------
__global__ __launch_bounds__(128) void attn_kernel(
    const ushort* __restrict__ qkv, ushort* __restrict__ out) {
  int head  = blockIdx.x;
  int token = blockIdx.y;
  int t = token >> 8;
  int h = (token >> 4) & 15;
  int w = token & 15;

  __shared__ float  q_s[HD];
  __shared__ float  k_s[WIN][HD + 1];
  __shared__ ushort v_s[WIN][HD + 2];
  __shared__ float  p_s[WIN];
  __shared__ float  red[4];

  int tid = threadIdx.x;
  if (tid < HD) q_s[tid] = bf2f(qkv[token * 2304 + head * HD + tid]);

  int hs = h - 2; hs = hs < 0 ? 0 : (hs > 11 ? 11 : hs);
  int wsb = w - 2; wsb = wsb < 0 ? 0 : (wsb > 11 ? 11 : wsb);

  for (int idx = tid; idx < WIN * HD; idx += 128) {
    int j = idx >> 6;
    int d = idx & 63;
    int jt = j / 25, jh = (j / 5) % 5, jw = j % 5;
    int it = t - 4 + jt; if (it < 0) it = 0;
    int nb = it * 256 + (hs + jh) * 16 + (wsb + jw);
    int base = nb * 2304 + head * HD + d;
    k_s[j][d] = bf2f(qkv[base + 768]);
    v_s[j][d] = qkv[base + 1536];
  }
  __syncthreads();

  float sc = -1e30f;
  if (tid < WIN) {
    int jt = tid / 25;
    float s = 0.0f;
#pragma unroll
    for (int d = 0; d < HD; ++d) s += q_s[d] * k_s[tid][d];
    sc = ((t - 4 + jt) >= 0) ? s * 0.125f : -1e9f;
  }
  float mx = sc;
  for (int off = 32; off; off >>= 1) mx = fmaxf(mx, __shfl_xor(mx, off, 64));
  if ((tid & 63) == 0) red[tid >> 6] = mx;
  __syncthreads();
  mx = fmaxf(red[0], red[1]);

  float p = (tid < WIN) ? expf(sc - mx) : 0.0f;
  float sm = p;
  for (int off = 32; off; off >>= 1) sm += __shfl_xor(sm, off, 64);
  if ((tid & 63) == 0) red[2 + (tid >> 6)] = sm;
  __syncthreads();
  float denom = red[2] + red[3];
  if (tid < WIN) p_s[tid] = p / denom;
  __syncthreads();

  if (tid < HD) {
    float o = 0.0f;
    for (int j = 0; j < WIN; ++j) o += p_s[j] * bf2f(v_s[j][tid]);
    out[token * DM + head * HD + tid] = f2bf(o);
  }
}

// ---------------- SwiGLU elementwise ----------------
__global__ __launch_bounds__(256) void swiglu_kernel(
    const ushort* __restrict__ h1, const ushort* __restrict__ h3,
    ushort* __restrict__ hg, int n) {
  int i = blockIdx.x * blockDim.x + threadIdx.x;
  if (i >= n) return;
  float a = bf2f(h1[i]);
  float b = bf2f(h3[i]);
  float s = a / (1.0f + __expf(-a));
  hg[i] = f2bf(s * b);
}

extern "C" void kernel_launch(void* const* d_in, const int* in_sizes, int n_in,
                              void* d_out, int out_size, void* d_ws, size_t ws_size,
                              hipStream_t stream) {
  const float* x_in    = (const float*)d_in[0];
  const float* norm1_w = (const float*)d_in[4];
  const float* norm2_w = (const float*)d_in[5];
  const float* qkv_w   = (const float*)d_in[6];
  const float* qkv_b   = (const float*)d_in[7];
  const float* out_w   = (const float*)d_in[8];
  const float* out_b   = (const float*)d_in[9];
  const float* w1      = (const float*)d_in[10];
  const float* w3      = (const float*)d_in[11];
  const float* w2      = (const float*)d_in[12];
  const float* fnw     = (const float*)d_in[13];

  char* p = (char*)d_ws;
  auto alloc = [&](size_t bytes) {
    char* r = p;
    p += (bytes + 255) & ~(size_t)255;
    return r;
  };
  ushort* wq_bf = (ushort*)alloc((size_t)2 * 2304 * 768 * 2);
  ushort* wo_bf = (ushort*)alloc((size_t)2 * 768 * 768 * 2);
  ushort* w1_bf = (ushort*)alloc((size_t)2 * 3072 * 768 * 2);
  ushort* w3_bf = (ushort*)alloc((size_t)2 * 3072 * 768 * 2);
  ushort* w2_bf = (ushort*)alloc((size_t)2 * 768 * 3072 * 2);
  float*  x     = (float*)alloc((size_t)NTOK * DM * 4);
  ushort* xn    = (ushort*)alloc((size_t)NTOK * DM * 2);
  ushort* qkvb  = (ushort*)alloc((size_t)NTOK * 2304 * 2);
  ushort* attnb = (ushort*)alloc((size_t)NTOK * DM * 2);
  ushort* h1    = (ushort*)alloc((size_t)NTOK * FFD * 2);
  ushort* h3    = (ushort*)alloc((size_t)NTOK * FFD * 2);
  ushort* hg    = (ushort*)alloc((size_t)NTOK * FFD * 2);

  hipMemcpyAsync(x, x_in, (size_t)NTOK * DM * 4, hipMemcpyDeviceToDevice, stream);

  auto cvt = [&](const float* in, ushort* out, int n) {
    int n4 = n / 4;
    int blocks = (n4 + 255) / 256;
    if (blocks > 2048) blocks = 2048;
    cvt_kernel<<<blocks, 256, 0, stream>>>(in, out, n4);
  };
  cvt(qkv_w, wq_bf, 2 * 2304 * 768);
  cvt(out_w, wo_bf, 2 * 768 * 768);
  cvt(w1,    w1_bf, 2 * 3072 * 768);
  cvt(w3,    w3_bf, 2 * 3072 * 768);
  cvt(w2,    w2_bf, 2 * 768 * 3072);

  for (int l = 0; l < 2; ++l) {
    rmsnorm_kernel<<<NTOK, 256, 0, stream>>>(x, norm1_w + l * DM, xn, nullptr);
    gemm64<<<dim3(2304 / 64, NTOK / 64), 64, 0, stream>>>(
        xn, wq_bf + (size_t)l * 2304 * 768, qkv_b + l * 2304, nullptr,
        nullptr, qkvb, NTOK, 2304, 768);
    attn_kernel<<<dim3(NH, NTOK), 128, 0, stream>>>(qkvb, attnb);
    gemm64<<<dim3(DM / 64, NTOK / 64), 64, 0, stream>>>(
        attnb, wo_bf + (size_t)l * 768 * 768, out_b + l * DM, x,
        x, nullptr, NTOK, DM, 768);
    rmsnorm_kernel<<<NTOK, 256, 0, stream>>>(x, norm2_w + l * DM, xn, nullptr);
    gemm64<<<dim3(FFD / 64, NTOK / 64), 64, 0, stream>>>(
        xn, w1_bf + (size_t)l * 3072 * 768, nullptr, nullptr,
        nullptr, h1, NTOK, FFD, 768);
    gemm64<<<dim3(FFD / 64, NTOK / 64), 64, 0, stream>>>(
        xn, w3_bf + (size_t)l * 3072 * 768, nullptr, nullptr,
        nullptr, h3, NTOK, FFD, 768);
    swiglu_kernel<<<(NTOK * FFD) / 256, 256, 0, stream>>>(h1, h3, hg, NTOK * FFD);
    gemm64<<<dim3(DM / 64, NTOK / 64), 64, 0, stream>>>(
        hg, w2_bf + (size_t)l * 768 * 3072, nullptr, x,
        x, nullptr, NTOK, DM, 3072);
  }
  rmsnorm_kernel<<<NTOK, 256, 0, stream>>>(x, fnw, nullptr, (float*)d_out);
}

// Round 4
// 465.355 us; speedup vs baseline: 1.7658x; 1.7658x over previous
//
#include <hip/hip_runtime.h>
#include <hip/hip_bf16.h>

#define DM   768
#define NH   12
#define HD   64
#define NTOK 1024
#define FFD  3072

typedef __bf16 bf16x8 __attribute__((ext_vector_type(8)));
typedef __attribute__((ext_vector_type(4))) float f32x4;

__device__ inline ushort f2bf(float f) {
  union { float f; uint u; } v; v.f = f;
  uint u = v.u;
  uint r = (u + 0x7FFFu + ((u >> 16) & 1u)) >> 16;
  return (ushort)r;
}
__device__ inline float bf2f(ushort h) {
  union { uint u; float f; } v; v.u = ((uint)h) << 16;
  return v.f;
}

// ---------------- fp32 -> bf16 weight conversion ----------------
__global__ void cvt_kernel(const float* __restrict__ in, ushort* __restrict__ out, int n4) {
  int i = blockIdx.x * blockDim.x + threadIdx.x;
  int stride = gridDim.x * blockDim.x;
  for (; i < n4; i += stride) {
    float4 v = ((const float4*)in)[i];
    ushort4 o;
    o.x = f2bf(v.x); o.y = f2bf(v.y); o.z = f2bf(v.z); o.w = f2bf(v.w);
    ((ushort4*)out)[i] = o;
  }
}

// ---------------- RMSNorm (one block per row) ----------------
__global__ __launch_bounds__(256) void rmsnorm_kernel(
    const float* __restrict__ x, const float* __restrict__ w,
    ushort* __restrict__ outB, float* __restrict__ outF) {
  int row = blockIdx.x;
  const float* xr = x + row * DM;
  int tid = threadIdx.x;
  float v0 = xr[tid], v1 = xr[tid + 256], v2 = xr[tid + 512];
  float ss = v0 * v0 + v1 * v1 + v2 * v2;
  for (int off = 32; off; off >>= 1) ss += __shfl_xor(ss, off, 64);
  __shared__ float red[4];
  int wid = tid >> 6;
  if ((tid & 63) == 0) red[wid] = ss;
  __syncthreads();
  float tot = red[0] + red[1] + red[2] + red[3];
  float scale = rsqrtf(tot * (1.0f / DM) + 1e-6f);
  float o0 = v0 * scale * w[tid];
  float o1 = v1 * scale * w[tid + 256];
  float o2 = v2 * scale * w[tid + 512];
  if (outB) {
    outB[row * DM + tid]       = f2bf(o0);
    outB[row * DM + tid + 256] = f2bf(o1);
    outB[row * DM + tid + 512] = f2bf(o2);
  } else {
    outF[row * DM + tid]       = o0;
    outF[row * DM + tid + 256] = o1;
    outF[row * DM + tid + 512] = o2;
  }
}

// ---------------- bf16 MFMA GEMM: C[M,N] = A @ B^T, 32x64 tile per wave ----------------
__global__ __launch_bounds__(64) void gemm32(
    const ushort* __restrict__ A, const ushort* __restrict__ B,
    const float* __restrict__ bias, const float* __restrict__ resid,
    float* __restrict__ outF, ushort* __restrict__ outB,
    int N, int K) {
  int n0 = blockIdx.x * 64;
  int m0 = blockIdx.y * 32;
  int lane = threadIdx.x;
  int r  = lane & 15;
  int kg = lane >> 4;

  f32x4 acc[2][4] = {};
  const ushort* Ab = A + (size_t)(m0 + r) * K + kg * 8;
  const ushort* Bb = B + (size_t)(n0 + r) * K + kg * 8;

  for (int k = 0; k < K; k += 32) {
    bf16x8 a0 = *(const bf16x8*)(Ab + k);
    bf16x8 a1 = *(const bf16x8*)(Ab + 16 * K + k);
    bf16x8 b[4];
#pragma unroll
    for (int i = 0; i < 4; ++i) b[i] = *(const bf16x8*)(Bb + i * 16 * K + k);
#pragma unroll
    for (int ni = 0; ni < 4; ++ni) {
      acc[0][ni] = __builtin_amdgcn_mfma_f32_16x16x32_bf16(a0, b[ni], acc[0][ni], 0, 0, 0);
      acc[1][ni] = __builtin_amdgcn_mfma_f32_16x16x32_bf16(a1, b[ni], acc[1][ni], 0, 0, 0);
    }
  }

  int crow = m0 + kg * 4;
  int ccol = n0 + r;
#pragma unroll
  for (int mi = 0; mi < 2; ++mi)
#pragma unroll
    for (int ni = 0; ni < 4; ++ni) {
      int col = ccol + ni * 16;
      float bv = bias ? bias[col] : 0.0f;
#pragma unroll
      for (int q = 0; q < 4; ++q) {
        int row = crow + mi * 16 + q;
        size_t idx = (size_t)row * N + col;
        float val = acc[mi][ni][q] + bv;
        if (resid) val += resid[idx];
        if (outF) outF[idx] = val;
        else      outB[idx] = f2bf(val);
      }
    }
}

// ---------------- fused FFN-up: hg = silu(x@w1^T) * (x@w3^T), 32x64 tile ----------------
__global__ __launch_bounds__(64) void gemm_ffn(
    const ushort* __restrict__ A, const ushort* __restrict__ B1,
    const ushort* __restrict__ B3, ushort* __restrict__ hg) {
  const int K = DM, N = FFD;
  int n0 = blockIdx.x * 64;
  int m0 = blockIdx.y * 32;
  int lane = threadIdx.x;
  int r  = lane & 15;
  int kg = lane >> 4;

  f32x4 acc1[2][4] = {};
  f32x4 acc3[2][4] = {};
  const ushort* Ab  = A  + (size_t)(m0 + r) * K + kg * 8;
  const ushort* B1b = B1 + (size_t)(n0 + r) * K + kg * 8;
  const ushort* B3b = B3 + (size_t)(n0 + r) * K + kg * 8;

  for (int k = 0; k < K; k += 32) {
    bf16x8 a0 = *(const bf16x8*)(Ab + k);
    bf16x8 a1 = *(const bf16x8*)(Ab + 16 * K + k);
    bf16x8 b1[4], b3[4];
#pragma unroll
    for (int i = 0; i < 4; ++i) {
      b1[i] = *(const bf16x8*)(B1b + i * 16 * K + k);
      b3[i] = *(const bf16x8*)(B3b + i * 16 * K + k);
    }
#pragma unroll
    for (int ni = 0; ni < 4; ++ni) {
      acc1[0][ni] = __builtin_amdgcn_mfma_f32_16x16x32_bf16(a0, b1[ni], acc1[0][ni], 0, 0, 0);
      acc1[1][ni] = __builtin_amdgcn_mfma_f32_16x16x32_bf16(a1, b1[ni], acc1[1][ni], 0, 0, 0);
      acc3[0][ni] = __builtin_amdgcn_mfma_f32_16x16x32_bf16(a0, b3[ni], acc3[0][ni], 0, 0, 0);
      acc3[1][ni] = __builtin_amdgcn_mfma_f32_16x16x32_bf16(a1, b3[ni], acc3[1][ni], 0, 0, 0);
    }
  }

  int crow = m0 + kg * 4;
  int ccol = n0 + r;
#pragma unroll
  for (int mi = 0; mi < 2; ++mi)
#pragma unroll
    for (int ni = 0; ni < 4; ++ni)
#pragma unroll
      for (int q = 0; q < 4; ++q) {
        int row = crow + mi * 16 + q;
        int col = ccol + ni * 16;
        float g = acc1[mi][ni][q];
        float s = g / (1.0f + __expf(-g));
        hg[(size_t)row * N + col] = f2bf(s * acc3[mi][ni][q]);
      }
}

// ---------------- 3D neighborhood attention: block per (t, h, head) ----------------
// Keys for all 16 w-queries at (t,h): t' in [0,t] x 5 h'-values x all 16 w'.
// Only the w-window mask is per-query. NK = (t+1)*80 <= 320.
__global__ __launch_bounds__(256) void attn_kernel(
    const ushort* __restrict__ qkv, ushort* __restrict__ out) {
  int head = blockIdx.x;
  int h    = blockIdx.y;
  int t    = blockIdx.z;
  int NT = (t + 1) * 5;                 // 16-key tiles
  int tid = threadIdx.x;
  int lane = tid & 63, wid = tid >> 6;
  int hstart = h - 2; hstart = hstart < 0 ? 0 : (hstart > 11 ? 11 : hstart);

  __shared__ ushort v_s[320 * 64];      // [j][d], bf16
  __shared__ ushort p_c[16][128];       // compressed P, bf16
  __shared__ float red_m[4][16], red_s[4][16];

  // ---- gather V (row j, d contiguous), 16B chunks ----
  for (int c = tid; c < NT * 128; c += 256) {
    int j = c >> 3, dc = c & 7;
    int tile = j >> 4;
    int tp = tile / 5, hh = tile - tp * 5;
    int nb = tp * 256 + (hstart + hh) * 16 + (j & 15);
    uint4 v = *(const uint4*)(qkv + (size_t)nb * 2304 + 1536 + head * 64 + dc * 8);
    *(uint4*)(v_s + j * 64 + dc * 8) = v;
  }

  // ---- Q fragments direct from global ----
  int c16 = lane & 15, kg = lane >> 4;
  const ushort* qp = qkv + (size_t)(t * 256 + h * 16 + c16) * 2304 + head * 64 + kg * 8;
  bf16x8 qa0 = *(const bf16x8*)qp;
  bf16x8 qa1 = *(const bf16x8*)(qp + 32);

  // ---- QK^T MFMA, K fragments direct from global; wave handles tiles wid, wid+4, ...
  f32x4 acc[5];
#pragma unroll
  for (int s = 0; s < 5; ++s) {
    f32x4 a = {};
    int ti = wid + s * 4;
    if (ti < NT) {
      int tp = ti / 5, hh = ti - tp * 5;
      const ushort* kp = qkv + (size_t)(tp * 256 + (hstart + hh) * 16 + c16) * 2304
                         + 768 + head * 64 + kg * 8;
      bf16x8 b0 = *(const bf16x8*)kp;
      bf16x8 b1 = *(const bf16x8*)(kp + 32);
      a = __builtin_amdgcn_mfma_f32_16x16x32_bf16(qa0, b0, a, 0, 0, 0);
      a = __builtin_amdgcn_mfma_f32_16x16x32_bf16(qa1, b1, a, 0, 0, 0);
    }
    acc[s] = a;
  }

  // ---- per-row masks: row q = kg*4+r (query w), col = c16 (key w') ----
  bool valid[4]; int wst[4];
#pragma unroll
  for (int r = 0; r < 4; ++r) {
    int q = kg * 4 + r;
    int ws = q - 2; ws = ws < 0 ? 0 : (ws > 11 ? 11 : ws);
    wst[r] = ws;
    valid[r] = (c16 >= ws) && (c16 < ws + 5);
  }

  // ---- masked row max ----
  float mloc[4];
#pragma unroll
  for (int r = 0; r < 4; ++r) mloc[r] = -1e30f;
#pragma unroll
  for (int s = 0; s < 5; ++s) {
    if (wid + s * 4 < NT) {
#pragma unroll
      for (int r = 0; r < 4; ++r)
        if (valid[r]) mloc[r] = fmaxf(mloc[r], acc[s][r]);
    }
  }
#pragma unroll
  for (int r = 0; r < 4; ++r)
    for (int off = 8; off; off >>= 1) mloc[r] = fmaxf(mloc[r], __shfl_xor(mloc[r], off, 64));
  if (c16 == 0) {
#pragma unroll
    for (int r = 0; r < 4; ++r) red_m[wid][kg * 4 + r] = mloc[r];
  }
  __syncthreads();

  float mq[4];
#pragma unroll
  for (int r = 0; r < 4; ++r) {
    int q = kg * 4 + r;
    mq[r] = fmaxf(fmaxf(red_m[0][q], red_m[1][q]), fmaxf(red_m[2][q], red_m[3][q]));
  }

  // ---- exp + row sum ----
  float pv[5][4];
  float ssum[4] = {0.f, 0.f, 0.f, 0.f};
#pragma unroll
  for (int s = 0; s < 5; ++s) {
    bool live = (wid + s * 4 < NT);
#pragma unroll
    for (int r = 0; r < 4; ++r) {
      float p = (live && valid[r]) ? __expf((acc[s][r] - mq[r]) * 0.125f) : 0.0f;
      pv[s][r] = p;
      ssum[r] += p;
    }
  }
#pragma unroll
  for (int r = 0; r < 4; ++r)
    for (int off = 8; off; off >>= 1) ssum[r] += __shfl_xor(ssum[r], off, 64);
  if (c16 == 0) {
#pragma unroll
    for (int r = 0; r < 4; ++r) red_s[wid][kg * 4 + r] = ssum[r];
  }
  __syncthreads();

  float inv[4];
#pragma unroll
  for (int r = 0; r < 4; ++r) {
    int q = kg * 4 + r;
    inv[r] = 1.0f / (red_s[0][q] + red_s[1][q] + red_s[2][q] + red_s[3][q]);
  }

  // ---- write compressed P: p_c[q][(t'*5+hh)*5 + wc] ----
#pragma unroll
  for (int s = 0; s < 5; ++s) {
    int ti = wid + s * 4;
    if (ti < NT) {
      int tp = ti / 5, hh = ti - tp * 5;
#pragma unroll
      for (int r = 0; r < 4; ++r) {
        if (valid[r]) {
          int wc = c16 - wst[r];
          p_c[kg * 4 + r][(tp * 5 + hh) * 5 + wc] = f2bf(pv[s][r] * inv[r]);
        }
      }
    }
  }
  __syncthreads();

  // ---- PV: thread = (q, dgroup of 4 d) ----
  int q  = tid >> 4;
  int dg = tid & 15;
  int ws2 = q - 2; ws2 = ws2 < 0 ? 0 : (ws2 > 11 ? 11 : ws2);
  float ox = 0.f, oy = 0.f, oz = 0.f, ow = 0.f;
  for (int tp = 0; tp <= t; ++tp) {
#pragma unroll
    for (int hh = 0; hh < 5; ++hh) {
      int jbase = tp * 80 + hh * 16 + ws2;
      const ushort* pb = &p_c[q][(tp * 5 + hh) * 5];
#pragma unroll
      for (int ww = 0; ww < 5; ++ww) {
        float p = bf2f(pb[ww]);
        uint2 v = *(const uint2*)(v_s + (jbase + ww) * 64 + dg * 4);
        ox += p * bf2f((ushort)(v.x & 0xffff));
        oy += p * bf2f((ushort)(v.x >> 16));
        oz += p * bf2f((ushort)(v.y & 0xffff));
        ow += p * bf2f((ushort)(v.y >> 16));
      }
    }
  }
  ushort4 ov;
  ov.x = f2bf(ox); ov.y = f2bf(oy); ov.z = f2bf(oz); ov.w = f2bf(ow);
  *(ushort4*)(out + (size_t)(t * 256 + h * 16 + q) * DM + head * 64 + dg * 4) = ov;
}

extern "C" void kernel_launch(void* const* d_in, const int* in_sizes, int n_in,
                              void* d_out, int out_size, void* d_ws, size_t ws_size,
                              hipStream_t stream) {
  const float* x_in    = (const float*)d_in[0];
  const float* norm1_w = (const float*)d_in[4];
  const float* norm2_w = (const float*)d_in[5];
  const float* qkv_w   = (const float*)d_in[6];
  const float* qkv_b   = (const float*)d_in[7];
  const float* out_w   = (const float*)d_in[8];
  const float* out_b   = (const float*)d_in[9];
  const float* w1      = (const float*)d_in[10];
  const float* w3      = (const float*)d_in[11];
  const float* w2      = (const float*)d_in[12];
  const float* fnw     = (const float*)d_in[13];

  char* p = (char*)d_ws;
  auto alloc = [&](size_t bytes) {
    char* r = p;
    p += (bytes + 255) & ~(size_t)255;
    return r;
  };
  ushort* wq_bf = (ushort*)alloc((size_t)2 * 2304 * 768 * 2);
  ushort* wo_bf = (ushort*)alloc((size_t)2 * 768 * 768 * 2);
  ushort* w1_bf = (ushort*)alloc((size_t)2 * 3072 * 768 * 2);
  ushort* w3_bf = (ushort*)alloc((size_t)2 * 3072 * 768 * 2);
  ushort* w2_bf = (ushort*)alloc((size_t)2 * 768 * 3072 * 2);
  float*  x     = (float*)alloc((size_t)NTOK * DM * 4);
  ushort* xn    = (ushort*)alloc((size_t)NTOK * DM * 2);
  ushort* qkvb  = (ushort*)alloc((size_t)NTOK * 2304 * 2);
  ushort* attnb = (ushort*)alloc((size_t)NTOK * DM * 2);
  ushort* hg    = (ushort*)alloc((size_t)NTOK * FFD * 2);

  hipMemcpyAsync(x, x_in, (size_t)NTOK * DM * 4, hipMemcpyDeviceToDevice, stream);

  auto cvt = [&](const float* in, ushort* out, int n) {
    int n4 = n / 4;
    int blocks = (n4 + 255) / 256;
    if (blocks > 2048) blocks = 2048;
    cvt_kernel<<<blocks, 256, 0, stream>>>(in, out, n4);
  };
  cvt(qkv_w, wq_bf, 2 * 2304 * 768);
  cvt(out_w, wo_bf, 2 * 768 * 768);
  cvt(w1,    w1_bf, 2 * 3072 * 768);
  cvt(w3,    w3_bf, 2 * 3072 * 768);
  cvt(w2,    w2_bf, 2 * 768 * 3072);

  for (int l = 0; l < 2; ++l) {
    rmsnorm_kernel<<<NTOK, 256, 0, stream>>>(x, norm1_w + l * DM, xn, nullptr);
    gemm32<<<dim3(2304 / 64, NTOK / 32), 64, 0, stream>>>(
        xn, wq_bf + (size_t)l * 2304 * 768, qkv_b + l * 2304, nullptr,
        nullptr, qkvb, 2304, 768);
    attn_kernel<<<dim3(NH, 16, 4), 256, 0, stream>>>(qkvb, attnb);
    gemm32<<<dim3(DM / 64, NTOK / 32), 64, 0, stream>>>(
        attnb, wo_bf + (size_t)l * 768 * 768, out_b + l * DM, x,
        x, nullptr, DM, 768);
    rmsnorm_kernel<<<NTOK, 256, 0, stream>>>(x, norm2_w + l * DM, xn, nullptr);
    gemm_ffn<<<dim3(FFD / 64, NTOK / 32), 64, 0, stream>>>(
        xn, w1_bf + (size_t)l * 3072 * 768, w3_bf + (size_t)l * 3072 * 768, hg);
    gemm32<<<dim3(DM / 64, NTOK / 32), 64, 0, stream>>>(
        hg, w2_bf + (size_t)l * 768 * 3072, nullptr, x,
        x, nullptr, DM, 3072);
  }
  rmsnorm_kernel<<<NTOK, 256, 0, stream>>>(x, fnw, nullptr, (float*)d_out);
}

// Round 5
// 433.020 us; speedup vs baseline: 1.8976x; 1.0747x over previous
//
#include <hip/hip_runtime.h>
#include <hip/hip_bf16.h>

#define DM   768
#define NH   12
#define HD   64
#define NTOK 1024
#define FFD  3072

typedef __bf16 bf16x8 __attribute__((ext_vector_type(8)));
typedef __attribute__((ext_vector_type(4))) float f32x4;

__device__ inline ushort f2bf(float f) {
  union { float f; uint u; } v; v.f = f;
  uint u = v.u;
  uint r = (u + 0x7FFFu + ((u >> 16) & 1u)) >> 16;
  return (ushort)r;
}
__device__ inline float bf2f(ushort h) {
  union { uint u; float f; } v; v.u = ((uint)h) << 16;
  return v.f;
}

// bijective XCD chunk swizzle (m204): blocks dispatch round-robin over 8 XCDs;
// map so each XCD gets a CONTIGUOUS range of tile ids (n-major -> B-panel locality).
__device__ inline int xcd_swz(int b, int nwg) {
  int q = nwg >> 3, r = nwg & 7;
  int x = b & 7, i = b >> 3;
  return (x < r) ? x * (q + 1) + i : r * (q + 1) + (x - r) * q + i;
}

// ---------------- fp32 -> bf16 weight conversion ----------------
__global__ void cvt_kernel(const float* __restrict__ in, ushort* __restrict__ out, int n4) {
  int i = blockIdx.x * blockDim.x + threadIdx.x;
  int stride = gridDim.x * blockDim.x;
  for (; i < n4; i += stride) {
    float4 v = ((const float4*)in)[i];
    ushort4 o;
    o.x = f2bf(v.x); o.y = f2bf(v.y); o.z = f2bf(v.z); o.w = f2bf(v.w);
    ((ushort4*)out)[i] = o;
  }
}

// ---------------- RMSNorm (one block per row) ----------------
__global__ __launch_bounds__(256) void rmsnorm_kernel(
    const float* __restrict__ x, const float* __restrict__ w,
    ushort* __restrict__ outB, float* __restrict__ outF) {
  int row = blockIdx.x;
  const float* xr = x + row * DM;
  int tid = threadIdx.x;
  float v0 = xr[tid], v1 = xr[tid + 256], v2 = xr[tid + 512];
  float ss = v0 * v0 + v1 * v1 + v2 * v2;
  for (int off = 32; off; off >>= 1) ss += __shfl_xor(ss, off, 64);
  __shared__ float red[4];
  int wid = tid >> 6;
  if ((tid & 63) == 0) red[wid] = ss;
  __syncthreads();
  float tot = red[0] + red[1] + red[2] + red[3];
  float scale = rsqrtf(tot * (1.0f / DM) + 1e-6f);
  float o0 = v0 * scale * w[tid];
  float o1 = v1 * scale * w[tid + 256];
  float o2 = v2 * scale * w[tid + 512];
  if (outB) {
    outB[row * DM + tid]       = f2bf(o0);
    outB[row * DM + tid + 256] = f2bf(o1);
    outB[row * DM + tid + 512] = f2bf(o2);
  } else {
    outF[row * DM + tid]       = o0;
    outF[row * DM + tid + 256] = o1;
    outF[row * DM + tid + 512] = o2;
  }
}

// ---------------- bf16 MFMA GEMM: C[M,N] (+)= A[M,K] @ B[N,K]^T ----------------
// 128 thr (2 waves), block tile 64x64, wave tile 32x64. 1D n-major grid + XCD swizzle.
// grid.y = S (split-K). fp32 out path uses atomicAdd (out must hold resid/0);
// bf16 out path requires S==1.
__global__ __launch_bounds__(128) void gemm_k(
    const ushort* __restrict__ A, const ushort* __restrict__ B,
    const float* __restrict__ bias,
    float* __restrict__ outF, ushort* __restrict__ outB,
    int M, int N, int K, int S) {
  int tile = xcd_swz(blockIdx.x, gridDim.x);
  int MB = M >> 6;
  int mblk = tile % MB, nblk = tile / MB;
  int m0 = mblk * 64, n0 = nblk * 64;
  int ks = blockIdx.y;
  int lane = threadIdx.x & 63, wid = threadIdx.x >> 6;
  int r = lane & 15, kg = lane >> 4;
  int Ks = K / S, k0 = ks * Ks, k1 = k0 + Ks;

  const ushort* Ab = A + (size_t)(m0 + wid * 32 + r) * K + kg * 8;
  const ushort* Bb = B + (size_t)(n0 + r) * K + kg * 8;

  f32x4 acc[2][4] = {};
  for (int k = k0; k < k1; k += 32) {
    bf16x8 a0 = *(const bf16x8*)(Ab + k);
    bf16x8 a1 = *(const bf16x8*)(Ab + 16 * K + k);
    bf16x8 b[4];
#pragma unroll
    for (int i = 0; i < 4; ++i) b[i] = *(const bf16x8*)(Bb + i * 16 * K + k);
#pragma unroll
    for (int ni = 0; ni < 4; ++ni) {
      acc[0][ni] = __builtin_amdgcn_mfma_f32_16x16x32_bf16(a0, b[ni], acc[0][ni], 0, 0, 0);
      acc[1][ni] = __builtin_amdgcn_mfma_f32_16x16x32_bf16(a1, b[ni], acc[1][ni], 0, 0, 0);
    }
  }

  int crow = m0 + wid * 32 + kg * 4;
  int ccol = n0 + r;
#pragma unroll
  for (int mi = 0; mi < 2; ++mi)
#pragma unroll
    for (int ni = 0; ni < 4; ++ni) {
      int col = ccol + ni * 16;
      float bv = (bias && ks == 0) ? bias[col] : 0.0f;
#pragma unroll
      for (int q = 0; q < 4; ++q) {
        int row = crow + mi * 16 + q;
        size_t idx = (size_t)row * N + col;
        float val = acc[mi][ni][q] + bv;
        if (outF) atomicAdd(outF + idx, val);
        else      outB[idx] = f2bf(val);
      }
    }
}

// ---------------- fused FFN-up: hg = silu(x@w1^T) * (x@w3^T) ----------------
__global__ __launch_bounds__(128) void gemm_ffn(
    const ushort* __restrict__ A, const ushort* __restrict__ B1,
    const ushort* __restrict__ B3, ushort* __restrict__ hg) {
  const int K = DM, N = FFD, MB = NTOK >> 6;
  int tile = xcd_swz(blockIdx.x, gridDim.x);
  int mblk = tile % MB, nblk = tile / MB;
  int m0 = mblk * 64, n0 = nblk * 64;
  int lane = threadIdx.x & 63, wid = threadIdx.x >> 6;
  int r = lane & 15, kg = lane >> 4;

  const ushort* Ab  = A  + (size_t)(m0 + wid * 32 + r) * K + kg * 8;
  const ushort* B1b = B1 + (size_t)(n0 + r) * K + kg * 8;
  const ushort* B3b = B3 + (size_t)(n0 + r) * K + kg * 8;

  f32x4 acc1[2][4] = {};
  f32x4 acc3[2][4] = {};
  for (int k = 0; k < K; k += 32) {
    bf16x8 a0 = *(const bf16x8*)(Ab + k);
    bf16x8 a1 = *(const bf16x8*)(Ab + 16 * K + k);
    bf16x8 b1[4], b3[4];
#pragma unroll
    for (int i = 0; i < 4; ++i) {
      b1[i] = *(const bf16x8*)(B1b + i * 16 * K + k);
      b3[i] = *(const bf16x8*)(B3b + i * 16 * K + k);
    }
#pragma unroll
    for (int ni = 0; ni < 4; ++ni) {
      acc1[0][ni] = __builtin_amdgcn_mfma_f32_16x16x32_bf16(a0, b1[ni], acc1[0][ni], 0, 0, 0);
      acc1[1][ni] = __builtin_amdgcn_mfma_f32_16x16x32_bf16(a1, b1[ni], acc1[1][ni], 0, 0, 0);
      acc3[0][ni] = __builtin_amdgcn_mfma_f32_16x16x32_bf16(a0, b3[ni], acc3[0][ni], 0, 0, 0);
      acc3[1][ni] = __builtin_amdgcn_mfma_f32_16x16x32_bf16(a1, b3[ni], acc3[1][ni], 0, 0, 0);
    }
  }

  int crow = m0 + wid * 32 + kg * 4;
  int ccol = n0 + r;
#pragma unroll
  for (int mi = 0; mi < 2; ++mi)
#pragma unroll
    for (int ni = 0; ni < 4; ++ni)
#pragma unroll
      for (int q = 0; q < 4; ++q) {
        int row = crow + mi * 16 + q;
        int col = ccol + ni * 16;
        float g = acc1[mi][ni][q];
        float s = g / (1.0f + __expf(-g));
        hg[(size_t)row * N + col] = f2bf(s * acc3[mi][ni][q]);
      }
}

// ---------------- 3D neighborhood attention: block per (t, h, head) ----------------
__global__ __launch_bounds__(256) void attn_kernel(
    const ushort* __restrict__ qkv, ushort* __restrict__ out) {
  int head = blockIdx.x;
  int h    = blockIdx.y;
  int t    = blockIdx.z;
  int NT = (t + 1) * 5;                 // 16-key tiles
  int tid = threadIdx.x;
  int lane = tid & 63, wid = tid >> 6;
  int hstart = h - 2; hstart = hstart < 0 ? 0 : (hstart > 11 ? 11 : hstart);

  __shared__ ushort v_s[320 * 64];      // [j][d], bf16
  __shared__ ushort p_c[16][128];       // compressed P, bf16
  __shared__ float red_m[4][16], red_s[4][16];

  for (int c = tid; c < NT * 128; c += 256) {
    int j = c >> 3, dc = c & 7;
    int tile = j >> 4;
    int tp = tile / 5, hh = tile - tp * 5;
    int nb = tp * 256 + (hstart + hh) * 16 + (j & 15);
    uint4 v = *(const uint4*)(qkv + (size_t)nb * 2304 + 1536 + head * 64 + dc * 8);
    *(uint4*)(v_s + j * 64 + dc * 8) = v;
  }

  int c16 = lane & 15, kg = lane >> 4;
  const ushort* qp = qkv + (size_t)(t * 256 + h * 16 + c16) * 2304 + head * 64 + kg * 8;
  bf16x8 qa0 = *(const bf16x8*)qp;
  bf16x8 qa1 = *(const bf16x8*)(qp + 32);

  f32x4 acc[5];
#pragma unroll
  for (int s = 0; s < 5; ++s) {
    f32x4 a = {};
    int ti = wid + s * 4;
    if (ti < NT) {
      int tp = ti / 5, hh = ti - tp * 5;
      const ushort* kp = qkv + (size_t)(tp * 256 + (hstart + hh) * 16 + c16) * 2304
                         + 768 + head * 64 + kg * 8;
      bf16x8 b0 = *(const bf16x8*)kp;
      bf16x8 b1 = *(const bf16x8*)(kp + 32);
      a = __builtin_amdgcn_mfma_f32_16x16x32_bf16(qa0, b0, a, 0, 0, 0);
      a = __builtin_amdgcn_mfma_f32_16x16x32_bf16(qa1, b1, a, 0, 0, 0);
    }
    acc[s] = a;
  }

  bool valid[4]; int wst[4];
#pragma unroll
  for (int r = 0; r < 4; ++r) {
    int q = kg * 4 + r;
    int ws = q - 2; ws = ws < 0 ? 0 : (ws > 11 ? 11 : ws);
    wst[r] = ws;
    valid[r] = (c16 >= ws) && (c16 < ws + 5);
  }

  float mloc[4];
#pragma unroll
  for (int r = 0; r < 4; ++r) mloc[r] = -1e30f;
#pragma unroll
  for (int s = 0; s < 5; ++s) {
    if (wid + s * 4 < NT) {
#pragma unroll
      for (int r = 0; r < 4; ++r)
        if (valid[r]) mloc[r] = fmaxf(mloc[r], acc[s][r]);
    }
  }
#pragma unroll
  for (int r = 0; r < 4; ++r)
    for (int off = 8; off; off >>= 1) mloc[r] = fmaxf(mloc[r], __shfl_xor(mloc[r], off, 64));
  if (c16 == 0) {
#pragma unroll
    for (int r = 0; r < 4; ++r) red_m[wid][kg * 4 + r] = mloc[r];
  }
  __syncthreads();

  float mq[4];
#pragma unroll
  for (int r = 0; r < 4; ++r) {
    int q = kg * 4 + r;
    mq[r] = fmaxf(fmaxf(red_m[0][q], red_m[1][q]), fmaxf(red_m[2][q], red_m[3][q]));
  }

  float pv[5][4];
  float ssum[4] = {0.f, 0.f, 0.f, 0.f};
#pragma unroll
  for (int s = 0; s < 5; ++s) {
    bool live = (wid + s * 4 < NT);
#pragma unroll
    for (int r = 0; r < 4; ++r) {
      float p = (live && valid[r]) ? __expf((acc[s][r] - mq[r]) * 0.125f) : 0.0f;
      pv[s][r] = p;
      ssum[r] += p;
    }
  }
#pragma unroll
  for (int r = 0; r < 4; ++r)
    for (int off = 8; off; off >>= 1) ssum[r] += __shfl_xor(ssum[r], off, 64);
  if (c16 == 0) {
#pragma unroll
    for (int r = 0; r < 4; ++r) red_s[wid][kg * 4 + r] = ssum[r];
  }
  __syncthreads();

  float inv[4];
#pragma unroll
  for (int r = 0; r < 4; ++r) {
    int q = kg * 4 + r;
    inv[r] = 1.0f / (red_s[0][q] + red_s[1][q] + red_s[2][q] + red_s[3][q]);
  }

#pragma unroll
  for (int s = 0; s < 5; ++s) {
    int ti = wid + s * 4;
    if (ti < NT) {
      int tp = ti / 5, hh = ti - tp * 5;
#pragma unroll
      for (int r = 0; r < 4; ++r) {
        if (valid[r]) {
          int wc = c16 - wst[r];
          p_c[kg * 4 + r][(tp * 5 + hh) * 5 + wc] = f2bf(pv[s][r] * inv[r]);
        }
      }
    }
  }
  __syncthreads();

  int q  = tid >> 4;
  int dg = tid & 15;
  int ws2 = q - 2; ws2 = ws2 < 0 ? 0 : (ws2 > 11 ? 11 : ws2);
  float ox = 0.f, oy = 0.f, oz = 0.f, ow = 0.f;
  for (int tp = 0; tp <= t; ++tp) {
#pragma unroll
    for (int hh = 0; hh < 5; ++hh) {
      int jbase = tp * 80 + hh * 16 + ws2;
      const ushort* pb = &p_c[q][(tp * 5 + hh) * 5];
#pragma unroll
      for (int ww = 0; ww < 5; ++ww) {
        float p = bf2f(pb[ww]);
        uint2 v = *(const uint2*)(v_s + (jbase + ww) * 64 + dg * 4);
        ox += p * bf2f((ushort)(v.x & 0xffff));
        oy += p * bf2f((ushort)(v.x >> 16));
        oz += p * bf2f((ushort)(v.y & 0xffff));
        ow += p * bf2f((ushort)(v.y >> 16));
      }
    }
  }
  ushort4 ov;
  ov.x = f2bf(ox); ov.y = f2bf(oy); ov.z = f2bf(oz); ov.w = f2bf(ow);
  *(ushort4*)(out + (size_t)(t * 256 + h * 16 + q) * DM + head * 64 + dg * 4) = ov;
}

extern "C" void kernel_launch(void* const* d_in, const int* in_sizes, int n_in,
                              void* d_out, int out_size, void* d_ws, size_t ws_size,
                              hipStream_t stream) {
  const float* x_in    = (const float*)d_in[0];
  const float* norm1_w = (const float*)d_in[4];
  const float* norm2_w = (const float*)d_in[5];
  const float* qkv_w   = (const float*)d_in[6];
  const float* qkv_b   = (const float*)d_in[7];
  const float* out_w   = (const float*)d_in[8];
  const float* out_b   = (const float*)d_in[9];
  const float* w1      = (const float*)d_in[10];
  const float* w3      = (const float*)d_in[11];
  const float* w2      = (const float*)d_in[12];
  const float* fnw     = (const float*)d_in[13];

  char* p = (char*)d_ws;
  auto alloc = [&](size_t bytes) {
    char* r = p;
    p += (bytes + 255) & ~(size_t)255;
    return r;
  };
  ushort* wq_bf = (ushort*)alloc((size_t)2 * 2304 * 768 * 2);
  ushort* wo_bf = (ushort*)alloc((size_t)2 * 768 * 768 * 2);
  ushort* w1_bf = (ushort*)alloc((size_t)2 * 3072 * 768 * 2);
  ushort* w3_bf = (ushort*)alloc((size_t)2 * 3072 * 768 * 2);
  ushort* w2_bf = (ushort*)alloc((size_t)2 * 768 * 3072 * 2);
  float*  x     = (float*)alloc((size_t)NTOK * DM * 4);
  ushort* xn    = (ushort*)alloc((size_t)NTOK * DM * 2);
  ushort* qkvb  = (ushort*)alloc((size_t)NTOK * 2304 * 2);
  ushort* attnb = (ushort*)alloc((size_t)NTOK * DM * 2);
  ushort* hg    = (ushort*)alloc((size_t)NTOK * FFD * 2);

  hipMemcpyAsync(x, x_in, (size_t)NTOK * DM * 4, hipMemcpyDeviceToDevice, stream);

  auto cvt = [&](const float* in, ushort* out, int n) {
    int n4 = n / 4;
    int blocks = (n4 + 255) / 256;
    if (blocks > 2048) blocks = 2048;
    cvt_kernel<<<blocks, 256, 0, stream>>>(in, out, n4);
  };
  cvt(qkv_w, wq_bf, 2 * 2304 * 768);
  cvt(out_w, wo_bf, 2 * 768 * 768);
  cvt(w1,    w1_bf, 2 * 3072 * 768);
  cvt(w3,    w3_bf, 2 * 3072 * 768);
  cvt(w2,    w2_bf, 2 * 768 * 3072);

  const int MB = NTOK / 64;  // 16
  for (int l = 0; l < 2; ++l) {
    rmsnorm_kernel<<<NTOK, 256, 0, stream>>>(x, norm1_w + l * DM, xn, nullptr);
    // QKV: N=2304, bf16 out, S=1
    gemm_k<<<dim3(MB * (2304 / 64), 1), 128, 0, stream>>>(
        xn, wq_bf + (size_t)l * 2304 * 768, qkv_b + l * 2304,
        nullptr, qkvb, NTOK, 2304, 768, 1);
    attn_kernel<<<dim3(NH, 16, 4), 256, 0, stream>>>(qkvb, attnb);
    // out-proj: N=768, atomic into x (holds resid), S=2
    gemm_k<<<dim3(MB * (DM / 64), 2), 128, 0, stream>>>(
        attnb, wo_bf + (size_t)l * 768 * 768, out_b + l * DM,
        x, nullptr, NTOK, DM, 768, 2);
    rmsnorm_kernel<<<NTOK, 256, 0, stream>>>(x, norm2_w + l * DM, xn, nullptr);
    gemm_ffn<<<dim3(MB * (FFD / 64)), 128, 0, stream>>>(
        xn, w1_bf + (size_t)l * 3072 * 768, w3_bf + (size_t)l * 3072 * 768, hg);
    // w2: N=768, K=3072, atomic into x, S=2
    gemm_k<<<dim3(MB * (DM / 64), 2), 128, 0, stream>>>(
        hg, w2_bf + (size_t)l * 768 * 3072, nullptr,
        x, nullptr, NTOK, DM, 3072, 2);
  }
  rmsnorm_kernel<<<NTOK, 256, 0, stream>>>(x, fnw, nullptr, (float*)d_out);
}